// Round 5
// baseline (1240.109 us; speedup 1.0000x reference)
//
#include <hip/hip_runtime.h>
#include <cstdint>
#include <cstddef>

// ---- constants ----
#define Bz 8
#define Lz 1024
#define Dz 512
#define Hz 8
#define NLz 6
#define DFz 2048
#define Mz (Bz*Lz)          // 8192 rows

typedef short bf16x8 __attribute__((ext_vector_type(8)));
typedef float f32x4  __attribute__((ext_vector_type(4)));

__device__ __forceinline__ short f2bf(float f) {
    unsigned u = __builtin_bit_cast(unsigned, f);
    u = (u + 0x7fff + ((u >> 16) & 1)) >> 16;
    return (short)u;
}

__device__ __forceinline__ float exp2_fast(float x) {
#if __has_builtin(__builtin_amdgcn_exp2f)
    return __builtin_amdgcn_exp2f(x);
#else
    return exp2f(x);
#endif
}

#define GLD16(gp, lp) __builtin_amdgcn_global_load_lds( \
    (const __attribute__((address_space(1))) void*)(gp), \
    (__attribute__((address_space(3))) void*)(lp), 16, 0, 0)

// ---------------- pos-emb add:  y = x + PE  ----------------
__global__ __launch_bounds__(256) void posadd_kernel(const float* __restrict__ x,
                                                     float* __restrict__ y) {
    int idx = blockIdx.x * 256 + threadIdx.x;       // < B*L*D
    int d   = idx & (Dz - 1);
    int pos = (idx >> 9) & (Lz - 1);
    int i2  = (d < Dz/2) ? d : d - Dz/2;
    float inv = __expf(-0.03597789207f * (float)i2);   // 10000^(-2i/D)
    float a = (float)pos * inv;
    float pe = (d < Dz/2) ? sinf(a) : cosf(a);
    y[idx] = x[idx] + pe;
}

// ---------------- LayerNorm (f32 in, bf16 out), one row per block ----------------
__global__ __launch_bounds__(256) void ln_kernel(const float* __restrict__ x,
                                                 const float* __restrict__ g,
                                                 const float* __restrict__ b,
                                                 short* __restrict__ out) {
    int row = blockIdx.x;
    int t = threadIdx.x;
    const float* xr = x + (size_t)row * Dz;
    float v0 = xr[t], v1 = xr[t + 256];
    float s = v0 + v1;
    #pragma unroll
    for (int off = 32; off; off >>= 1) s += __shfl_xor(s, off, 64);
    __shared__ float red[4];
    int w = t >> 6, l = t & 63;
    if (l == 0) red[w] = s;
    __syncthreads();
    float m = (red[0] + red[1] + red[2] + red[3]) * (1.0f / Dz);
    float d0 = v0 - m, d1 = v1 - m;
    float s2 = d0 * d0 + d1 * d1;
    #pragma unroll
    for (int off = 32; off; off >>= 1) s2 += __shfl_xor(s2, off, 64);
    __syncthreads();
    if (l == 0) red[w] = s2;
    __syncthreads();
    float var = (red[0] + red[1] + red[2] + red[3]) * (1.0f / Dz);
    float rs = rsqrtf(var + 1e-3f);
    out[(size_t)row * Dz + t]       = f2bf(d0 * rs * g[t] + b[t]);
    out[(size_t)row * Dz + t + 256] = f2bf(d1 * rs * g[t + 256] + b[t + 256]);
}

// ---------------- weight transpose + cast: dst[n][k] = bf16(src[k][n]), batched over layers -------
__global__ __launch_bounds__(256) void transpose_bf16_kernel(const float* __restrict__ src,
                                                             short* __restrict__ dst,
                                                             int K, int N,
                                                             long srcLS, long dstLS, int rowOff) {
    __shared__ float tile[32][33];
    int tx = threadIdx.x & 31, ty = threadIdx.x >> 5;
    int bx = blockIdx.x, by = blockIdx.y, z = blockIdx.z;
    const float* s = src + (size_t)z * srcLS;
    short* d = dst + (size_t)z * dstLS;
    #pragma unroll
    for (int i = 0; i < 4; i++)
        tile[ty + i * 8][tx] = s[(size_t)(by * 32 + ty + i * 8) * N + bx * 32 + tx];
    __syncthreads();
    #pragma unroll
    for (int i = 0; i < 4; i++)
        d[(size_t)(rowOff + bx * 32 + ty + i * 8) * K + by * 32 + tx] = f2bf(tile[tx][ty + i * 8]);
}

// ---------------- V transpose: qkv[b*L+l][1024 + h*64 + d] -> vbt[(b*8+h)*64 + d][l] ------------
__global__ __launch_bounds__(256) void vtrans_kernel(const short* __restrict__ qkv,
                                                     short* __restrict__ vbt) {
    int lt = blockIdx.x, bh = blockIdx.y;
    int b = bh >> 3, h = bh & 7;
    __shared__ short tile[64][72];
    int t = threadIdx.x;
    int l = t >> 2, c4 = t & 3;
    #pragma unroll
    for (int p = 0; p < 2; p++) {
        int dd = (c4 + p * 4) * 8;
        *(uint4*)&tile[l][dd] =
            *(const uint4*)(qkv + ((size_t)(b * Lz + lt * 64 + l)) * 1536 + 1024 + h * 64 + dd);
    }
    __syncthreads();
    int d = t >> 2;
    #pragma unroll
    for (int p = 0; p < 2; p++) {
        int lc = (c4 + p * 4) * 8;
        union { uint4 u; short s[8]; } o;
        #pragma unroll
        for (int j = 0; j < 8; j++) o.s[j] = tile[lc + j][d];
        *(uint4*)(vbt + ((size_t)(bh * 64 + d)) * Lz + lt * 64 + lc) = o.u;
    }
}

// ---------------- GEMM: C[M,N] = A[M,K] * W[K,N], W given transposed (Bt[N][K]), bf16 in, f32 acc
// Tile 128 x TN (TN = 128 or 64), K-step 64, DOUBLE-BUFFERED LDS, ONE barrier per K-step:
//   prologue stage(buf0) -> loop { stage(buf^1, next); compute(buf); syncthreads } -> compute(last)
// The barrier's implicit vmcnt(0) drain now waits on loads that overlapped a full compute phase.
// LDS kept LINEAR for global_load_lds; bank conflicts avoided by XOR-swizzling the GLOBAL
// source column at stage time and the chunk index at read time (both-sides involution).
// MODE 0: out bf16 (no bias)                    -> outb
// MODE 1: outf[idx] += acc                      (residual in-place, f32)
// MODE 2: out bf16 = relu(acc + bias)           -> outb
// MODE 3: outf[idx] += acc + bias               (residual in-place, f32)
// MODE 4: outf2[idx] = outf[idx] + acc + bias   (residual, write to separate f32 buffer)
template<int MODE, int TN>
__global__ __launch_bounds__(256, (TN == 64) ? 3 : 2)
void gemm_bt(const short* __restrict__ A,
             const short* __restrict__ Bt,
             short* __restrict__ outb,
             float* __restrict__ outf,
             float* __restrict__ outf2,
             const float* __restrict__ bias,
             int M, int N, int K) {
    constexpr int NI = TN / 32;          // 4 or 2
    constexpr int ASZ = 128 * 64;        // shorts per A buffer (16 KB)
    constexpr int BSZ = TN * 64;         // shorts per B buffer (16 or 8 KB)
    __shared__ __attribute__((aligned(16))) short As[2 * ASZ];
    __shared__ __attribute__((aligned(16))) short Bs[2 * BSZ];
    int t = threadIdx.x;
    int m0 = blockIdx.x * 128, n0 = blockIdx.y * TN;
    int w = t >> 6, l = t & 63;
    int wm = (w >> 1) * 64, wn = (w & 1) * (TN / 2);
    int lr = l & 15, lq = l >> 4;
    f32x4 acc[4][NI] = {};
    // staging: thread t fills linear LDS bytes [16t,16t+16) of each 32-row chunk;
    // linear slot = (row sr, chunk t&7) -> fetch logical chunk (t&7)^(sr&7)
    int sr = t >> 3;                          // row 0..31 within a 32-row chunk
    int sc = ((t & 7) ^ (sr & 7)) * 8;        // pre-swizzled source column (shorts)

    auto stage = [&](int cur, int kk) {
        short* Ad = As + cur * ASZ;
        short* Bd = Bs + cur * BSZ;
        #pragma unroll
        for (int i = 0; i < 4; i++)
            GLD16(A + (size_t)(m0 + sr + i * 32) * K + kk + sc, Ad + i * 2048 + t * 8);
        #pragma unroll
        for (int i = 0; i < TN / 32; i++)
            GLD16(Bt + (size_t)(n0 + sr + i * 32) * K + kk + sc, Bd + i * 2048 + t * 8);
    };
    auto compute = [&](int cur) {
        const short* Ab = As + cur * ASZ;
        const short* Bb = Bs + cur * BSZ;
        bf16x8 af[4][2], bfr[NI][2];
        #pragma unroll
        for (int i = 0; i < 4; i++) {
            int row = wm + i * 16 + lr;
            const short* rp = Ab + row * 64;
            af[i][0] = *(const bf16x8*)(rp + ((lq ^ (row & 7)) * 8));
            af[i][1] = *(const bf16x8*)(rp + (((4 + lq) ^ (row & 7)) * 8));
        }
        #pragma unroll
        for (int i = 0; i < NI; i++) {
            int row = wn + i * 16 + lr;
            const short* rp = Bb + row * 64;
            bfr[i][0] = *(const bf16x8*)(rp + ((lq ^ (row & 7)) * 8));
            bfr[i][1] = *(const bf16x8*)(rp + (((4 + lq) ^ (row & 7)) * 8));
        }
        #pragma unroll
        for (int mi = 0; mi < 4; mi++)
            #pragma unroll
            for (int ni = 0; ni < NI; ni++) {
                acc[mi][ni] = __builtin_amdgcn_mfma_f32_16x16x32_bf16(af[mi][0], bfr[ni][0], acc[mi][ni], 0, 0, 0);
                acc[mi][ni] = __builtin_amdgcn_mfma_f32_16x16x32_bf16(af[mi][1], bfr[ni][1], acc[mi][ni], 0, 0, 0);
            }
    };

    int nt = K >> 6;
    stage(0, 0);
    __syncthreads();                          // buf0 staged
    int cur = 0;
    for (int tix = 0; tix < nt - 1; ++tix) {
        stage(cur ^ 1, (tix + 1) << 6);       // issue next tile (in flight under compute)
        compute(cur);
        __syncthreads();                      // drains vmcnt(0)+lgkmcnt(0); next buf ready
        cur ^= 1;
    }
    compute(cur);                             // last tile (already staged + barriered)

    #pragma unroll
    for (int mi = 0; mi < 4; mi++)
        #pragma unroll
        for (int ni = 0; ni < NI; ni++) {
            int col = n0 + wn + ni * 16 + lr;
            float bv = (MODE == 2 || MODE == 3 || MODE == 4) ? bias[col] : 0.0f;
            #pragma unroll
            for (int r = 0; r < 4; r++) {
                int row = m0 + wm + mi * 16 + lq * 4 + r;
                size_t idx = (size_t)row * N + col;
                float v = acc[mi][ni][r];
                if (MODE == 0)      outb[idx] = f2bf(v);
                else if (MODE == 1) outf[idx] += v;
                else if (MODE == 2) outb[idx] = f2bf(fmaxf(v + bv, 0.0f));
                else if (MODE == 3) outf[idx] += v + bv;
                else                outf2[idx] = outf[idx] + v + bv;
            }
        }
}

// ---------------- attention fragment: softmax + P->LDS + PV ----------------
__device__ __forceinline__ void attn_frag(f32x4* sacc, const float* biask,
                                          float* mr, float* lsum, f32x4* oacc,
                                          short* Pw, const short* Vs,
                                          int lr, int lq, bf16x8 onesf) {
    const float SC2 = 0.18033688f;            // (1/8) * log2(e)
    float p[8][4];
    #pragma unroll
    for (int r = 0; r < 4; r++) {
        float mx = -1e30f;
        #pragma unroll
        for (int kt = 0; kt < 8; kt++) {
            p[kt][r] = sacc[kt][r] * SC2 + biask[kt];
            mx = fmaxf(mx, p[kt][r]);
        }
        mx = fmaxf(mx, __shfl_xor(mx, 1, 64));
        mx = fmaxf(mx, __shfl_xor(mx, 2, 64));
        mx = fmaxf(mx, __shfl_xor(mx, 4, 64));
        mx = fmaxf(mx, __shfl_xor(mx, 8, 64));
        float mn = fmaxf(mr[r], mx);
        float alpha = exp2_fast(mr[r] - mn);
        mr[r] = mn;
        #pragma unroll
        for (int kt = 0; kt < 8; kt++)
            p[kt][r] = exp2_fast(p[kt][r] - mn);
        lsum[r] *= alpha;
        #pragma unroll
        for (int ni = 0; ni < 4; ni++) oacc[ni][r] *= alpha;
    }
    #pragma unroll
    for (int kt = 0; kt < 8; kt++)
        #pragma unroll
        for (int r = 0; r < 4; r++)
            Pw[(lq * 4 + r) * 136 + kt * 16 + lr] = f2bf(p[kt][r]);
    f32x4 sums = {};
    #pragma unroll
    for (int c = 0; c < 4; c++) {
        bf16x8 pf = *(const bf16x8*)(Pw + lr * 136 + c * 32 + lq * 8);
        sums = __builtin_amdgcn_mfma_f32_16x16x32_bf16(pf, onesf, sums, 0, 0, 0);
        #pragma unroll
        for (int ni = 0; ni < 4; ni++) {
            bf16x8 vf = *(const bf16x8*)(Vs + (ni * 16 + lr) * 136 + c * 32 + lq * 8);
            oacc[ni] = __builtin_amdgcn_mfma_f32_16x16x32_bf16(pf, vf, oacc[ni], 0, 0, 0);
        }
    }
    #pragma unroll
    for (int r = 0; r < 4; r++) lsum[r] += sums[r];
}

// ---------------- fused attention, 128 q-rows x 128-key tiles, online softmax ----------------
// qkv: [M][1536] bf16 (q|k|v);  vbt: [(b*8+h)*64 + d][L] bf16;  o: [M][512] bf16
// Each wave: 32 q-rows (2 fragments of 16, processed sequentially per key-tile).
// Grid is (bh, qt) so linear id = bh + 64*qt -> XCD = bh % 8: all blocks sharing one
// head's K/V land on the same XCD (per-XCD K/V working set 2 MB <= 4 MB L2).
__global__ __launch_bounds__(256, 2) void attn_kernel(const short* __restrict__ qkv,
                                                      const short* __restrict__ vbt,
                                                      const int* __restrict__ lengths,
                                                      short* __restrict__ o) {
    __shared__ __attribute__((aligned(16))) short Ks[128 * 72];   // 18432 B
    __shared__ __attribute__((aligned(16))) short Vs[64 * 136];   // 17408 B
    __shared__ __attribute__((aligned(16))) short Ps[4][16 * 136];// 17408 B
    int qt = blockIdx.y;            // q-tile of 128 rows
    int bh = blockIdx.x;
    int b = bh >> 3, h = bh & 7;
    int len = lengths[b];
    int t = threadIdx.x, w = t >> 6, l = t & 63;
    int lr = l & 15, lq = l >> 4;

    const short* q0 = qkv + (size_t)(b * Lz + qt * 128 + w * 32 + lr) * 1536 + h * 64 + lq * 8;
    bf16x8 qf0a = *(const bf16x8*)(q0);
    bf16x8 qf0b = *(const bf16x8*)(q0 + 32);
    bf16x8 qf1a = *(const bf16x8*)(q0 + 16 * 1536);
    bf16x8 qf1b = *(const bf16x8*)(q0 + 16 * 1536 + 32);

    int kkey = t >> 3, kd8 = (t & 7) * 8;
    int vd = t >> 4, vk8 = (t & 15) * 8;
    const short* kbaseg = qkv + (size_t)(b * Lz) * 1536 + 512 + h * 64;
    const short* vbaseg = vbt + (size_t)(bh * 64) * Lz;

    float mr0[4] = {-1e30f, -1e30f, -1e30f, -1e30f}, ls0[4] = {0.f, 0.f, 0.f, 0.f};
    float mr1[4] = {-1e30f, -1e30f, -1e30f, -1e30f}, ls1[4] = {0.f, 0.f, 0.f, 0.f};
    f32x4 oacc0[4] = {}, oacc1[4] = {};
    bf16x8 onesf = {0x3F80, 0x3F80, 0x3F80, 0x3F80, 0x3F80, 0x3F80, 0x3F80, 0x3F80};

    uint4 kreg[4], vreg[4];
    #pragma unroll
    for (int i = 0; i < 4; i++)
        kreg[i] = *(const uint4*)(kbaseg + (size_t)(i * 32 + kkey) * 1536 + kd8);

    short* Pw = &Ps[w][0];
    int ntiles = (len + 127) >> 7;
    for (int tix = 0; tix < ntiles; tix++) {
        int k0 = tix << 7;
        __syncthreads();                       // [A] prev-tile Ks/Vs/P reads complete
        #pragma unroll
        for (int i = 0; i < 4; i++)
            *(uint4*)(Ks + (i * 32 + kkey) * 72 + kd8) = kreg[i];
        __syncthreads();                       // [B] K staged
        // V global loads for current tile (hidden under QK MFMAs)
        #pragma unroll
        for (int i = 0; i < 4; i++)
            vreg[i] = *(const uint4*)(vbaseg + (size_t)(i * 16 + vd) * Lz + k0 + vk8);
        // QK^T fragment 0
        f32x4 sacc[8] = {};
        #pragma unroll
        for (int kt = 0; kt < 8; kt++) {
            bf16x8 kf0 = *(const bf16x8*)(Ks + (kt * 16 + lr) * 72 + lq * 8);
            bf16x8 kf1 = *(const bf16x8*)(Ks + (kt * 16 + lr) * 72 + 32 + lq * 8);
            sacc[kt] = __builtin_amdgcn_mfma_f32_16x16x32_bf16(qf0a, kf0, sacc[kt], 0, 0, 0);
            sacc[kt] = __builtin_amdgcn_mfma_f32_16x16x32_bf16(qf0b, kf1, sacc[kt], 0, 0, 0);
        }
        // K prefetch for next tile
        if (tix + 1 < ntiles) {
            #pragma unroll
            for (int i = 0; i < 4; i++)
                kreg[i] = *(const uint4*)(kbaseg + (size_t)(k0 + 128 + i * 32 + kkey) * 1536 + kd8);
        }
        // V stage into LDS
        #pragma unroll
        for (int i = 0; i < 4; i++)
            *(uint4*)(Vs + (i * 16 + vd) * 136 + vk8) = vreg[i];
        float biask[8];
        #pragma unroll
        for (int kt = 0; kt < 8; kt++)
            biask[kt] = ((k0 + kt * 16 + lr) < len) ? 0.0f : -1e30f;
        __syncthreads();                       // [C] Vs staged; Ks stays valid until next [A]
        // fragment 0: softmax + P + PV
        attn_frag(sacc, biask, mr0, ls0, oacc0, Pw, Vs, lr, lq, onesf);
        // QK^T fragment 1 (Ks still resident)
        #pragma unroll
        for (int kt = 0; kt < 8; kt++) {
            bf16x8 kf0 = *(const bf16x8*)(Ks + (kt * 16 + lr) * 72 + lq * 8);
            bf16x8 kf1 = *(const bf16x8*)(Ks + (kt * 16 + lr) * 72 + 32 + lq * 8);
            f32x4 s2 = {};
            s2 = __builtin_amdgcn_mfma_f32_16x16x32_bf16(qf1a, kf0, s2, 0, 0, 0);
            s2 = __builtin_amdgcn_mfma_f32_16x16x32_bf16(qf1b, kf1, s2, 0, 0, 0);
            sacc[kt] = s2;
        }
        attn_frag(sacc, biask, mr1, ls1, oacc1, Pw, Vs, lr, lq, onesf);
    }
    #pragma unroll
    for (int ni = 0; ni < 4; ni++)
        #pragma unroll
        for (int r = 0; r < 4; r++) {
            int q = qt * 128 + w * 32 + lq * 4 + r;
            size_t base = (size_t)(b * Lz + q) * Dz + h * 64 + ni * 16 + lr;
            o[base]             = f2bf(oacc0[ni][r] / ls0[r]);
            o[base + 16 * Dz]   = f2bf(oacc1[ni][r] / ls1[r]);
        }
}

extern "C" void kernel_launch(void* const* d_in, const int* in_sizes, int n_in,
                              void* d_out, int out_size, void* d_ws, size_t ws_size,
                              hipStream_t stream) {
    const float* x_in    = (const float*)d_in[0];
    const int*   lengths = (const int*)d_in[1];
    const float* Wq   = (const float*)d_in[2];
    const float* Wk   = (const float*)d_in[3];
    const float* Wv   = (const float*)d_in[4];
    const float* Wo   = (const float*)d_in[5];
    const float* ln1g = (const float*)d_in[6];
    const float* ln1b = (const float*)d_in[7];
    const float* ln2g = (const float*)d_in[8];
    const float* ln2b = (const float*)d_in[9];
    const float* w1   = (const float*)d_in[10];
    const float* b1   = (const float*)d_in[11];
    const float* w2   = (const float*)d_in[12];
    const float* b2   = (const float*)d_in[13];

    size_t off = 0;
    auto alloc = [&](size_t bytes) {
        void* p = (char*)d_ws + off;
        off += (bytes + 255) & ~(size_t)255;
        return p;
    };
    float* x_work = (float*)alloc((size_t)Mz * Dz * 4);
    short* hbuf   = (short*)alloc((size_t)Mz * Dz * 2);        // LN out / attention out
    short* qkvb   = (short*)alloc((size_t)Mz * 1536 * 2);
    short* f1b    = (short*)alloc((size_t)Mz * DFz * 2);
    short* vbt    = (short*)alloc((size_t)Bz * Hz * 64 * Lz * 2);
    short* wqkvT  = (short*)alloc((size_t)NLz * 1536 * Dz * 2);
    short* woT    = (short*)alloc((size_t)NLz * Dz * Dz * 2);
    short* w1T    = (short*)alloc((size_t)NLz * DFz * Dz * 2);
    short* w2T    = (short*)alloc((size_t)NLz * Dz * DFz * 2);

    dim3 tb(256);
    // weight transposes (per call; same work every call)
    transpose_bf16_kernel<<<dim3(16, 16, NLz), tb, 0, stream>>>(Wq, wqkvT, Dz, Dz, (long)Dz*Dz, (long)1536*Dz, 0);
    transpose_bf16_kernel<<<dim3(16, 16, NLz), tb, 0, stream>>>(Wk, wqkvT, Dz, Dz, (long)Dz*Dz, (long)1536*Dz, 512);
    transpose_bf16_kernel<<<dim3(16, 16, NLz), tb, 0, stream>>>(Wv, wqkvT, Dz, Dz, (long)Dz*Dz, (long)1536*Dz, 1024);
    transpose_bf16_kernel<<<dim3(16, 16, NLz), tb, 0, stream>>>(Wo, woT, Dz, Dz, (long)Dz*Dz, (long)Dz*Dz, 0);
    transpose_bf16_kernel<<<dim3(64, 16, NLz), tb, 0, stream>>>(w1, w1T, Dz, DFz, (long)Dz*DFz, (long)DFz*Dz, 0);
    transpose_bf16_kernel<<<dim3(16, 64, NLz), tb, 0, stream>>>(w2, w2T, DFz, Dz, (long)DFz*Dz, (long)Dz*DFz, 0);

    posadd_kernel<<<dim3(Mz * Dz / 256), tb, 0, stream>>>(x_in, x_work);

    for (int lyr = 0; lyr < NLz; lyr++) {
        const short* wqkvL = wqkvT + (size_t)lyr * 1536 * Dz;
        const short* woL   = woT   + (size_t)lyr * Dz * Dz;
        const short* w1L   = w1T   + (size_t)lyr * DFz * Dz;
        const short* w2L   = w2T   + (size_t)lyr * Dz * DFz;

        ln_kernel<<<dim3(Mz), tb, 0, stream>>>(x_work, ln1g + lyr * Dz, ln1b + lyr * Dz, hbuf);
        gemm_bt<0,128><<<dim3(Mz/128, 1536/128), tb, 0, stream>>>(hbuf, wqkvL, qkvb, nullptr, nullptr, nullptr, Mz, 1536, Dz);
        vtrans_kernel<<<dim3(Lz/64, Bz*Hz), tb, 0, stream>>>(qkvb, vbt);
        attn_kernel<<<dim3(Bz*Hz, Lz/128), tb, 0, stream>>>(qkvb, vbt, lengths, hbuf);
        gemm_bt<1,64><<<dim3(Mz/128, Dz/64), tb, 0, stream>>>(hbuf, woL, nullptr, x_work, nullptr, nullptr, Mz, Dz, Dz);
        ln_kernel<<<dim3(Mz), tb, 0, stream>>>(x_work, ln2g + lyr * Dz, ln2b + lyr * Dz, hbuf);
        gemm_bt<2,128><<<dim3(Mz/128, DFz/128), tb, 0, stream>>>(hbuf, w1L, f1b, nullptr, nullptr, b1 + lyr * DFz, Mz, DFz, Dz);
        if (lyr < NLz - 1)
            gemm_bt<3,64><<<dim3(Mz/128, Dz/64), tb, 0, stream>>>(f1b, w2L, nullptr, x_work, nullptr, b2 + lyr * Dz, Mz, Dz, DFz);
        else
            gemm_bt<4,64><<<dim3(Mz/128, Dz/64), tb, 0, stream>>>(f1b, w2L, nullptr, x_work, (float*)d_out, b2 + lyr * Dz, Mz, Dz, DFz);
    }
}

// Round 6
// 1048.221 us; speedup vs baseline: 1.1831x; 1.1831x over previous
//
#include <hip/hip_runtime.h>
#include <cstdint>
#include <cstddef>

// ---- constants ----
#define Bz 8
#define Lz 1024
#define Dz 512
#define Hz 8
#define NLz 6
#define DFz 2048
#define Mz (Bz*Lz)          // 8192 rows

typedef short bf16x8 __attribute__((ext_vector_type(8)));
typedef float f32x4  __attribute__((ext_vector_type(4)));
typedef short s16x4  __attribute__((ext_vector_type(4)));

__device__ __forceinline__ short f2bf(float f) {
    unsigned u = __builtin_bit_cast(unsigned, f);
    u = (u + 0x7fff + ((u >> 16) & 1)) >> 16;
    return (short)u;
}

__device__ __forceinline__ float exp2_fast(float x) {
#if __has_builtin(__builtin_amdgcn_exp2f)
    return __builtin_amdgcn_exp2f(x);
#else
    return exp2f(x);
#endif
}

#define GLD16(gp, lp) __builtin_amdgcn_global_load_lds( \
    (const __attribute__((address_space(1))) void*)(gp), \
    (__attribute__((address_space(3))) void*)(lp), 16, 0, 0)

// ---------------- pos-emb add:  y = x + PE  ----------------
__global__ __launch_bounds__(256) void posadd_kernel(const float* __restrict__ x,
                                                     float* __restrict__ y) {
    int idx = blockIdx.x * 256 + threadIdx.x;       // < B*L*D
    int d   = idx & (Dz - 1);
    int pos = (idx >> 9) & (Lz - 1);
    int i2  = (d < Dz/2) ? d : d - Dz/2;
    float inv = __expf(-0.03597789207f * (float)i2);   // 10000^(-2i/D)
    float a = (float)pos * inv;
    float pe = (d < Dz/2) ? sinf(a) : cosf(a);
    y[idx] = x[idx] + pe;
}

// ---------------- LayerNorm (f32 in, bf16 out), ONE ROW PER WAVE ----------------
// 4 rows/block, float4 loads (16 B/lane), pure shuffle reduce: no LDS, no barriers.
__global__ __launch_bounds__(256) void ln_kernel(const float* __restrict__ x,
                                                 const float* __restrict__ g,
                                                 const float* __restrict__ b,
                                                 short* __restrict__ out) {
    int w = threadIdx.x >> 6, l = threadIdx.x & 63;
    int row = blockIdx.x * 4 + w;
    const float* xr = x + (size_t)row * Dz;
    f32x4 a0 = *(const f32x4*)(xr + l * 4);
    f32x4 a1 = *(const f32x4*)(xr + 256 + l * 4);
    float s = (a0[0] + a0[1]) + (a0[2] + a0[3]) + (a1[0] + a1[1]) + (a1[2] + a1[3]);
    #pragma unroll
    for (int off = 32; off; off >>= 1) s += __shfl_xor(s, off, 64);
    float m = s * (1.0f / Dz);
    f32x4 d0, d1;
    float s2 = 0.0f;
    #pragma unroll
    for (int j = 0; j < 4; j++) { d0[j] = a0[j] - m; s2 += d0[j] * d0[j]; }
    #pragma unroll
    for (int j = 0; j < 4; j++) { d1[j] = a1[j] - m; s2 += d1[j] * d1[j]; }
    #pragma unroll
    for (int off = 32; off; off >>= 1) s2 += __shfl_xor(s2, off, 64);
    float rs = rsqrtf(s2 * (1.0f / Dz) + 1e-3f);
    f32x4 g0 = *(const f32x4*)(g + l * 4);
    f32x4 g1 = *(const f32x4*)(g + 256 + l * 4);
    f32x4 b0 = *(const f32x4*)(b + l * 4);
    f32x4 b1 = *(const f32x4*)(b + 256 + l * 4);
    s16x4 o0, o1;
    #pragma unroll
    for (int j = 0; j < 4; j++) o0[j] = f2bf(d0[j] * rs * g0[j] + b0[j]);
    #pragma unroll
    for (int j = 0; j < 4; j++) o1[j] = f2bf(d1[j] * rs * g1[j] + b1[j]);
    *(s16x4*)(out + (size_t)row * Dz + l * 4)       = o0;
    *(s16x4*)(out + (size_t)row * Dz + 256 + l * 4) = o1;
}

// ---------------- weight transpose + cast: dst[n][k] = bf16(src[k][n]), batched over layers -------
__global__ __launch_bounds__(256) void transpose_bf16_kernel(const float* __restrict__ src,
                                                             short* __restrict__ dst,
                                                             int K, int N,
                                                             long srcLS, long dstLS, int rowOff) {
    __shared__ float tile[32][33];
    int tx = threadIdx.x & 31, ty = threadIdx.x >> 5;
    int bx = blockIdx.x, by = blockIdx.y, z = blockIdx.z;
    const float* s = src + (size_t)z * srcLS;
    short* d = dst + (size_t)z * dstLS;
    #pragma unroll
    for (int i = 0; i < 4; i++)
        tile[ty + i * 8][tx] = s[(size_t)(by * 32 + ty + i * 8) * N + bx * 32 + tx];
    __syncthreads();
    #pragma unroll
    for (int i = 0; i < 4; i++)
        d[(size_t)(rowOff + bx * 32 + ty + i * 8) * K + by * 32 + tx] = f2bf(tile[tx][ty + i * 8]);
}

// ---------------- V transpose: qkv[b*L+l][1024 + h*64 + d] -> vbt[(b*8+h)*64 + d][l] ------------
__global__ __launch_bounds__(256) void vtrans_kernel(const short* __restrict__ qkv,
                                                     short* __restrict__ vbt) {
    int lt = blockIdx.x, bh = blockIdx.y;
    int b = bh >> 3, h = bh & 7;
    __shared__ short tile[64][72];
    int t = threadIdx.x;
    int l = t >> 2, c4 = t & 3;
    #pragma unroll
    for (int p = 0; p < 2; p++) {
        int dd = (c4 + p * 4) * 8;
        *(uint4*)&tile[l][dd] =
            *(const uint4*)(qkv + ((size_t)(b * Lz + lt * 64 + l)) * 1536 + 1024 + h * 64 + dd);
    }
    __syncthreads();
    int d = t >> 2;
    #pragma unroll
    for (int p = 0; p < 2; p++) {
        int lc = (c4 + p * 4) * 8;
        union { uint4 u; short s[8]; } o;
        #pragma unroll
        for (int j = 0; j < 8; j++) o.s[j] = tile[lc + j][d];
        *(uint4*)(vbt + ((size_t)(bh * 64 + d)) * Lz + lt * 64 + lc) = o.u;
    }
}

// ---------------- GEMM: C[M,N] = A[M,K] * W[K,N], W given transposed (Bt[N][K]), bf16 in, f32 acc
// Tile 128 x TN (TN = 128 or 64), K-step 64, SINGLE-buffer (round-4 proven structure:
// cross-block TLP at 3+ blocks/CU hides the stage drain; dbuf regressed by halving residency).
// LDS kept LINEAR for global_load_lds; bank conflicts avoided by XOR-swizzling the GLOBAL
// source column at stage time and the chunk index at read time (both-sides involution).
// MODE 0: out bf16 (no bias)                    -> outb
// MODE 1: outf[idx] += acc                      (residual in-place, f32)
// MODE 2: out bf16 = relu(acc + bias)           -> outb
// MODE 3: outf[idx] += acc + bias               (residual in-place, f32)
// MODE 4: outf2[idx] = outf[idx] + acc + bias   (residual, write to separate f32 buffer)
template<int MODE, int TN>
__global__ __launch_bounds__(256, 2)
void gemm_bt(const short* __restrict__ A,
             const short* __restrict__ Bt,
             short* __restrict__ outb,
             float* __restrict__ outf,
             float* __restrict__ outf2,
             const float* __restrict__ bias,
             int M, int N, int K) {
    constexpr int NI = TN / 32;          // 4 or 2
    __shared__ __attribute__((aligned(16))) short As[128 * 64];   // 16 KB
    __shared__ __attribute__((aligned(16))) short Bs[TN * 64];    // 16 or 8 KB
    int t = threadIdx.x;
    int m0 = blockIdx.x * 128, n0 = blockIdx.y * TN;
    int w = t >> 6, l = t & 63;
    int wm = (w >> 1) * 64, wn = (w & 1) * (TN / 2);
    int lr = l & 15, lq = l >> 4;
    f32x4 acc[4][NI] = {};
    // staging: thread t fills linear LDS bytes [16t,16t+16) of each 32-row chunk;
    // linear slot = (row sr, chunk t&7) -> fetch logical chunk (t&7)^(sr&7)
    int sr = t >> 3;                          // row 0..31 within a 32-row chunk
    int sc = ((t & 7) ^ (sr & 7)) * 8;        // pre-swizzled source column (shorts)
    for (int kk = 0; kk < K; kk += 64) {
        #pragma unroll
        for (int i = 0; i < 4; i++)
            GLD16(A + (size_t)(m0 + sr + i * 32) * K + kk + sc, As + i * 2048 + t * 8);
        #pragma unroll
        for (int i = 0; i < TN / 32; i++)
            GLD16(Bt + (size_t)(n0 + sr + i * 32) * K + kk + sc, Bs + i * 2048 + t * 8);
        __syncthreads();
        bf16x8 af[4][2], bfr[NI][2];
        #pragma unroll
        for (int i = 0; i < 4; i++) {
            int row = wm + i * 16 + lr;
            const short* rp = As + row * 64;
            af[i][0] = *(const bf16x8*)(rp + ((lq ^ (row & 7)) * 8));
            af[i][1] = *(const bf16x8*)(rp + (((4 + lq) ^ (row & 7)) * 8));
        }
        #pragma unroll
        for (int i = 0; i < NI; i++) {
            int row = wn + i * 16 + lr;
            const short* rp = Bs + row * 64;
            bfr[i][0] = *(const bf16x8*)(rp + ((lq ^ (row & 7)) * 8));
            bfr[i][1] = *(const bf16x8*)(rp + (((4 + lq) ^ (row & 7)) * 8));
        }
        #pragma unroll
        for (int mi = 0; mi < 4; mi++)
            #pragma unroll
            for (int ni = 0; ni < NI; ni++) {
                acc[mi][ni] = __builtin_amdgcn_mfma_f32_16x16x32_bf16(af[mi][0], bfr[ni][0], acc[mi][ni], 0, 0, 0);
                acc[mi][ni] = __builtin_amdgcn_mfma_f32_16x16x32_bf16(af[mi][1], bfr[ni][1], acc[mi][ni], 0, 0, 0);
            }
        __syncthreads();
    }
    #pragma unroll
    for (int mi = 0; mi < 4; mi++)
        #pragma unroll
        for (int ni = 0; ni < NI; ni++) {
            int col = n0 + wn + ni * 16 + lr;
            float bv = (MODE == 2 || MODE == 3 || MODE == 4) ? bias[col] : 0.0f;
            #pragma unroll
            for (int r = 0; r < 4; r++) {
                int row = m0 + wm + mi * 16 + lq * 4 + r;
                size_t idx = (size_t)row * N + col;
                float v = acc[mi][ni][r];
                if (MODE == 0)      outb[idx] = f2bf(v);
                else if (MODE == 1) outf[idx] += v;
                else if (MODE == 2) outb[idx] = f2bf(fmaxf(v + bv, 0.0f));
                else if (MODE == 3) outf[idx] += v + bv;
                else                outf2[idx] = outf[idx] + v + bv;
            }
        }
}

// ---------------- attention fragment: softmax + P->LDS + PV ----------------
__device__ __forceinline__ void attn_frag(f32x4* sacc, const float* biask,
                                          float* mr, float* lsum, f32x4* oacc,
                                          short* Pw, const short* Vs,
                                          int lr, int lq, bf16x8 onesf) {
    const float SC2 = 0.18033688f;            // (1/8) * log2(e)
    float p[8][4];
    #pragma unroll
    for (int r = 0; r < 4; r++) {
        float mx = -1e30f;
        #pragma unroll
        for (int kt = 0; kt < 8; kt++) {
            p[kt][r] = sacc[kt][r] * SC2 + biask[kt];
            mx = fmaxf(mx, p[kt][r]);
        }
        mx = fmaxf(mx, __shfl_xor(mx, 1, 64));
        mx = fmaxf(mx, __shfl_xor(mx, 2, 64));
        mx = fmaxf(mx, __shfl_xor(mx, 4, 64));
        mx = fmaxf(mx, __shfl_xor(mx, 8, 64));
        float mn = fmaxf(mr[r], mx);
        float alpha = exp2_fast(mr[r] - mn);
        mr[r] = mn;
        #pragma unroll
        for (int kt = 0; kt < 8; kt++)
            p[kt][r] = exp2_fast(p[kt][r] - mn);
        lsum[r] *= alpha;
        #pragma unroll
        for (int ni = 0; ni < 4; ni++) oacc[ni][r] *= alpha;
    }
    #pragma unroll
    for (int kt = 0; kt < 8; kt++)
        #pragma unroll
        for (int r = 0; r < 4; r++)
            Pw[(lq * 4 + r) * 136 + kt * 16 + lr] = f2bf(p[kt][r]);
    f32x4 sums = {};
    #pragma unroll
    for (int c = 0; c < 4; c++) {
        bf16x8 pf = *(const bf16x8*)(Pw + lr * 136 + c * 32 + lq * 8);
        sums = __builtin_amdgcn_mfma_f32_16x16x32_bf16(pf, onesf, sums, 0, 0, 0);
        #pragma unroll
        for (int ni = 0; ni < 4; ni++) {
            bf16x8 vf = *(const bf16x8*)(Vs + (ni * 16 + lr) * 136 + c * 32 + lq * 8);
            oacc[ni] = __builtin_amdgcn_mfma_f32_16x16x32_bf16(pf, vf, oacc[ni], 0, 0, 0);
        }
    }
    #pragma unroll
    for (int r = 0; r < 4; r++) lsum[r] += sums[r];
}

// ---------------- fused attention, 128 q-rows x 128-key tiles, online softmax ----------------
// qkv: [M][1536] bf16 (q|k|v);  vbt: [(b*8+h)*64 + d][L] bf16;  o: [M][512] bf16
// Each wave: 32 q-rows (2 fragments of 16, processed sequentially per key-tile).
// Grid is (bh, qt) so linear id = bh + 64*qt -> XCD = bh % 8: all blocks sharing one
// head's K/V land on the same XCD (per-XCD K/V working set 2 MB <= 4 MB L2).
__global__ __launch_bounds__(256, 2) void attn_kernel(const short* __restrict__ qkv,
                                                      const short* __restrict__ vbt,
                                                      const int* __restrict__ lengths,
                                                      short* __restrict__ o) {
    __shared__ __attribute__((aligned(16))) short Ks[128 * 72];   // 18432 B
    __shared__ __attribute__((aligned(16))) short Vs[64 * 136];   // 17408 B
    __shared__ __attribute__((aligned(16))) short Ps[4][16 * 136];// 17408 B
    int qt = blockIdx.y;            // q-tile of 128 rows
    int bh = blockIdx.x;
    int b = bh >> 3, h = bh & 7;
    int len = lengths[b];
    int t = threadIdx.x, w = t >> 6, l = t & 63;
    int lr = l & 15, lq = l >> 4;

    const short* q0 = qkv + (size_t)(b * Lz + qt * 128 + w * 32 + lr) * 1536 + h * 64 + lq * 8;
    bf16x8 qf0a = *(const bf16x8*)(q0);
    bf16x8 qf0b = *(const bf16x8*)(q0 + 32);
    bf16x8 qf1a = *(const bf16x8*)(q0 + 16 * 1536);
    bf16x8 qf1b = *(const bf16x8*)(q0 + 16 * 1536 + 32);

    int kkey = t >> 3, kd8 = (t & 7) * 8;
    int vd = t >> 4, vk8 = (t & 15) * 8;
    const short* kbaseg = qkv + (size_t)(b * Lz) * 1536 + 512 + h * 64;
    const short* vbaseg = vbt + (size_t)(bh * 64) * Lz;

    float mr0[4] = {-1e30f, -1e30f, -1e30f, -1e30f}, ls0[4] = {0.f, 0.f, 0.f, 0.f};
    float mr1[4] = {-1e30f, -1e30f, -1e30f, -1e30f}, ls1[4] = {0.f, 0.f, 0.f, 0.f};
    f32x4 oacc0[4] = {}, oacc1[4] = {};
    bf16x8 onesf = {0x3F80, 0x3F80, 0x3F80, 0x3F80, 0x3F80, 0x3F80, 0x3F80, 0x3F80};

    uint4 kreg[4], vreg[4];
    #pragma unroll
    for (int i = 0; i < 4; i++)
        kreg[i] = *(const uint4*)(kbaseg + (size_t)(i * 32 + kkey) * 1536 + kd8);

    short* Pw = &Ps[w][0];
    int ntiles = (len + 127) >> 7;
    for (int tix = 0; tix < ntiles; tix++) {
        int k0 = tix << 7;
        __syncthreads();                       // [A] prev-tile Ks/Vs/P reads complete
        #pragma unroll
        for (int i = 0; i < 4; i++)
            *(uint4*)(Ks + (i * 32 + kkey) * 72 + kd8) = kreg[i];
        __syncthreads();                       // [B] K staged
        // V global loads for current tile (hidden under QK MFMAs)
        #pragma unroll
        for (int i = 0; i < 4; i++)
            vreg[i] = *(const uint4*)(vbaseg + (size_t)(i * 16 + vd) * Lz + k0 + vk8);
        // QK^T fragment 0
        f32x4 sacc[8] = {};
        #pragma unroll
        for (int kt = 0; kt < 8; kt++) {
            bf16x8 kf0 = *(const bf16x8*)(Ks + (kt * 16 + lr) * 72 + lq * 8);
            bf16x8 kf1 = *(const bf16x8*)(Ks + (kt * 16 + lr) * 72 + 32 + lq * 8);
            sacc[kt] = __builtin_amdgcn_mfma_f32_16x16x32_bf16(qf0a, kf0, sacc[kt], 0, 0, 0);
            sacc[kt] = __builtin_amdgcn_mfma_f32_16x16x32_bf16(qf0b, kf1, sacc[kt], 0, 0, 0);
        }
        // K prefetch for next tile
        if (tix + 1 < ntiles) {
            #pragma unroll
            for (int i = 0; i < 4; i++)
                kreg[i] = *(const uint4*)(kbaseg + (size_t)(k0 + 128 + i * 32 + kkey) * 1536 + kd8);
        }
        // V stage into LDS
        #pragma unroll
        for (int i = 0; i < 4; i++)
            *(uint4*)(Vs + (i * 16 + vd) * 136 + vk8) = vreg[i];
        float biask[8];
        #pragma unroll
        for (int kt = 0; kt < 8; kt++)
            biask[kt] = ((k0 + kt * 16 + lr) < len) ? 0.0f : -1e30f;
        __syncthreads();                       // [C] Vs staged; Ks stays valid until next [A]
        // fragment 0: softmax + P + PV
        attn_frag(sacc, biask, mr0, ls0, oacc0, Pw, Vs, lr, lq, onesf);
        // QK^T fragment 1 (Ks still resident)
        #pragma unroll
        for (int kt = 0; kt < 8; kt++) {
            bf16x8 kf0 = *(const bf16x8*)(Ks + (kt * 16 + lr) * 72 + lq * 8);
            bf16x8 kf1 = *(const bf16x8*)(Ks + (kt * 16 + lr) * 72 + 32 + lq * 8);
            f32x4 s2 = {};
            s2 = __builtin_amdgcn_mfma_f32_16x16x32_bf16(qf1a, kf0, s2, 0, 0, 0);
            s2 = __builtin_amdgcn_mfma_f32_16x16x32_bf16(qf1b, kf1, s2, 0, 0, 0);
            sacc[kt] = s2;
        }
        attn_frag(sacc, biask, mr1, ls1, oacc1, Pw, Vs, lr, lq, onesf);
    }
    #pragma unroll
    for (int ni = 0; ni < 4; ni++)
        #pragma unroll
        for (int r = 0; r < 4; r++) {
            int q = qt * 128 + w * 32 + lq * 4 + r;
            size_t base = (size_t)(b * Lz + q) * Dz + h * 64 + ni * 16 + lr;
            o[base]             = f2bf(oacc0[ni][r] / ls0[r]);
            o[base + 16 * Dz]   = f2bf(oacc1[ni][r] / ls1[r]);
        }
}

extern "C" void kernel_launch(void* const* d_in, const int* in_sizes, int n_in,
                              void* d_out, int out_size, void* d_ws, size_t ws_size,
                              hipStream_t stream) {
    const float* x_in    = (const float*)d_in[0];
    const int*   lengths = (const int*)d_in[1];
    const float* Wq   = (const float*)d_in[2];
    const float* Wk   = (const float*)d_in[3];
    const float* Wv   = (const float*)d_in[4];
    const float* Wo   = (const float*)d_in[5];
    const float* ln1g = (const float*)d_in[6];
    const float* ln1b = (const float*)d_in[7];
    const float* ln2g = (const float*)d_in[8];
    const float* ln2b = (const float*)d_in[9];
    const float* w1   = (const float*)d_in[10];
    const float* b1   = (const float*)d_in[11];
    const float* w2   = (const float*)d_in[12];
    const float* b2   = (const float*)d_in[13];

    size_t off = 0;
    auto alloc = [&](size_t bytes) {
        void* p = (char*)d_ws + off;
        off += (bytes + 255) & ~(size_t)255;
        return p;
    };
    float* x_work = (float*)alloc((size_t)Mz * Dz * 4);
    short* hbuf   = (short*)alloc((size_t)Mz * Dz * 2);        // LN out / attention out
    short* qkvb   = (short*)alloc((size_t)Mz * 1536 * 2);
    short* f1b    = (short*)alloc((size_t)Mz * DFz * 2);
    short* vbt    = (short*)alloc((size_t)Bz * Hz * 64 * Lz * 2);
    short* wqkvT  = (short*)alloc((size_t)NLz * 1536 * Dz * 2);
    short* woT    = (short*)alloc((size_t)NLz * Dz * Dz * 2);
    short* w1T    = (short*)alloc((size_t)NLz * DFz * Dz * 2);
    short* w2T    = (short*)alloc((size_t)NLz * Dz * DFz * 2);

    dim3 tb(256);
    // weight transposes (per call; same work every call)
    transpose_bf16_kernel<<<dim3(16, 16, NLz), tb, 0, stream>>>(Wq, wqkvT, Dz, Dz, (long)Dz*Dz, (long)1536*Dz, 0);
    transpose_bf16_kernel<<<dim3(16, 16, NLz), tb, 0, stream>>>(Wk, wqkvT, Dz, Dz, (long)Dz*Dz, (long)1536*Dz, 512);
    transpose_bf16_kernel<<<dim3(16, 16, NLz), tb, 0, stream>>>(Wv, wqkvT, Dz, Dz, (long)Dz*Dz, (long)1536*Dz, 1024);
    transpose_bf16_kernel<<<dim3(16, 16, NLz), tb, 0, stream>>>(Wo, woT, Dz, Dz, (long)Dz*Dz, (long)Dz*Dz, 0);
    transpose_bf16_kernel<<<dim3(64, 16, NLz), tb, 0, stream>>>(w1, w1T, Dz, DFz, (long)Dz*DFz, (long)DFz*Dz, 0);
    transpose_bf16_kernel<<<dim3(16, 64, NLz), tb, 0, stream>>>(w2, w2T, DFz, Dz, (long)DFz*Dz, (long)Dz*DFz, 0);

    posadd_kernel<<<dim3(Mz * Dz / 256), tb, 0, stream>>>(x_in, x_work);

    for (int lyr = 0; lyr < NLz; lyr++) {
        const short* wqkvL = wqkvT + (size_t)lyr * 1536 * Dz;
        const short* woL   = woT   + (size_t)lyr * Dz * Dz;
        const short* w1L   = w1T   + (size_t)lyr * DFz * Dz;
        const short* w2L   = w2T   + (size_t)lyr * Dz * DFz;

        ln_kernel<<<dim3(Mz/4), tb, 0, stream>>>(x_work, ln1g + lyr * Dz, ln1b + lyr * Dz, hbuf);
        gemm_bt<0,128><<<dim3(Mz/128, 1536/128), tb, 0, stream>>>(hbuf, wqkvL, qkvb, nullptr, nullptr, nullptr, Mz, 1536, Dz);
        vtrans_kernel<<<dim3(Lz/64, Bz*Hz), tb, 0, stream>>>(qkvb, vbt);
        attn_kernel<<<dim3(Bz*Hz, Lz/128), tb, 0, stream>>>(qkvb, vbt, lengths, hbuf);
        gemm_bt<1,64><<<dim3(Mz/128, Dz/64), tb, 0, stream>>>(hbuf, woL, nullptr, x_work, nullptr, nullptr, Mz, Dz, Dz);
        ln_kernel<<<dim3(Mz/4), tb, 0, stream>>>(x_work, ln2g + lyr * Dz, ln2b + lyr * Dz, hbuf);
        gemm_bt<2,128><<<dim3(Mz/128, DFz/128), tb, 0, stream>>>(hbuf, w1L, f1b, nullptr, nullptr, b1 + lyr * DFz, Mz, DFz, Dz);
        if (lyr < NLz - 1)
            gemm_bt<3,64><<<dim3(Mz/128, Dz/64), tb, 0, stream>>>(f1b, w2L, nullptr, x_work, nullptr, b2 + lyr * Dz, Mz, Dz, DFz);
        else
            gemm_bt<4,64><<<dim3(Mz/128, Dz/64), tb, 0, stream>>>(f1b, w2L, nullptr, x_work, (float*)d_out, b2 + lyr * Dz, Mz, Dz, DFz);
    }
}